// Round 1
// baseline (5193.157 us; speedup 1.0000x reference)
//
#include <hip/hip_runtime.h>

#define DEV __device__ __forceinline__

typedef _Float16 f16;
typedef _Float16 f16x8 __attribute__((ext_vector_type(8)));
typedef _Float16 f16x2 __attribute__((ext_vector_type(2)));
typedef float f32x4 __attribute__((ext_vector_type(4)));

static constexpr int K0P = 416;   // layer0 input dim 400 padded to 13*32
static constexpr int GN  = 3200;  // 2 dirs * 4 gates * 400
static constexpr int HH  = 400;   // per-direction hidden

// ---------------- math helpers ----------------
DEV float sigf(float x) { return 1.f / (1.f + __expf(-x)); }
DEV float tanhf_(float x) {
  x = fminf(10.f, fmaxf(-10.f, x));
  float e = __expf(2.f * x);
  return (e - 1.f) / (e + 1.f);
}

#if __has_builtin(__builtin_amdgcn_fdot2)
DEV float fdot2u(unsigned w, unsigned h, float acc) {
  return __builtin_amdgcn_fdot2(__builtin_bit_cast(f16x2, w),
                                __builtin_bit_cast(f16x2, h), acc, false);
}
#else
DEV float fdot2u(unsigned w, unsigned h, float acc) {
  f16x2 a = __builtin_bit_cast(f16x2, w), b = __builtin_bit_cast(f16x2, h);
  return acc + (float)a[0] * (float)b[0] + (float)a[1] * (float)b[1];
}
#endif

// ---------------- embedding gather -> x0 f16 [4096][416] ----------------
__global__ void embed_k(const int* __restrict__ wt, const int* __restrict__ pt,
                        const float* __restrict__ we, const float* __restrict__ pe,
                        f16* __restrict__ x0)
{
  const int r = blockIdx.x;       // b*T+t
  const int tid = threadIdx.x;    // 128
  const int w = wt[r], p = pt[r];
  const float* wrow = we + (size_t)w * 300;
  const float* prow = pe + (size_t)p * 100;
  f16* xr = x0 + (size_t)r * K0P;
  for (int k = tid; k < K0P; k += 128) {
    float v = (k < 300) ? wrow[k] : (k < 400 ? prow[k - 300] : 0.f);
    xr[k] = (f16)v;
  }
}

// ---------------- f32 -> f16 with optional K padding ----------------
__global__ void convpad_k(const float* __restrict__ src, f16* __restrict__ dst,
                          int rows, int K, int KP)
{
  const size_t total = (size_t)rows * KP;
  for (size_t i = (size_t)blockIdx.x * blockDim.x + threadIdx.x; i < total;
       i += (size_t)gridDim.x * blockDim.x) {
    int r = (int)(i / KP), k = (int)(i % KP);
    dst[i] = (f16)(k < K ? src[(size_t)r * K + k] : 0.f);
  }
}

__global__ void biascat_k(const float* __restrict__ bh, const float* __restrict__ bm,
                          float* __restrict__ bhm)
{
  int i = threadIdx.x;  // 1024
  bhm[i] = i < 512 ? bh[i] : bm[i - 512];
}

// ---------------- GEMM: C[M][N] = A[M][KP] * B[N][KP]^T + bias[n], f16 in, f32 out
// 128x128 tile, BK=32, 4 waves in 2x2, each wave 64x64 via 4x4 mfma_f32_16x16x32_f16
__global__ __launch_bounds__(256) void gemm_f16_nt(
    const f16* __restrict__ A, const f16* __restrict__ Bw,
    const float* __restrict__ bias, float* __restrict__ C,
    int M, int N, int KP)
{
  __shared__ __align__(16) f16 As[128][40];   // +8 pad to spread banks
  __shared__ __align__(16) f16 Bs[128][40];
  const int tid = threadIdx.x;
  const int bn = blockIdx.x, bm = blockIdx.y;
  const int lane = tid & 63, wid = tid >> 6;
  const int wr = wid >> 1, wc = wid & 1;
  const int srow = tid >> 1, shalf = tid & 1;
  const f16* Ap = A + (size_t)(bm * 128 + srow) * KP + shalf * 16;
  const f16* Bp = Bw + (size_t)(bn * 128 + srow) * KP + shalf * 16;
  const int fr = lane & 15, fq = lane >> 4;
  f32x4 acc[4][4] = {};
  for (int kt = 0; kt < KP; kt += 32) {
    __syncthreads();
    *(uint4*)&As[srow][shalf * 16]     = *(const uint4*)(Ap + kt);
    *(uint4*)&As[srow][shalf * 16 + 8] = *(const uint4*)(Ap + kt + 8);
    *(uint4*)&Bs[srow][shalf * 16]     = *(const uint4*)(Bp + kt);
    *(uint4*)&Bs[srow][shalf * 16 + 8] = *(const uint4*)(Bp + kt + 8);
    __syncthreads();
    f16x8 af[4], bf[4];
    #pragma unroll
    for (int m = 0; m < 4; ++m) af[m] = *(const f16x8*)&As[wr * 64 + m * 16 + fr][fq * 8];
    #pragma unroll
    for (int n = 0; n < 4; ++n) bf[n] = *(const f16x8*)&Bs[wc * 64 + n * 16 + fr][fq * 8];
    #pragma unroll
    for (int m = 0; m < 4; ++m)
      #pragma unroll
      for (int n = 0; n < 4; ++n)
        acc[m][n] = __builtin_amdgcn_mfma_f32_16x16x32_f16(af[m], bf[n], acc[m][n], 0, 0, 0);
  }
  #pragma unroll
  for (int n = 0; n < 4; ++n) {
    const int gn = bn * 128 + wc * 64 + n * 16 + fr;
    const float bv = bias ? bias[gn] : 0.f;
    #pragma unroll
    for (int m = 0; m < 4; ++m) {
      const size_t gm = (size_t)bm * 128 + wr * 64 + m * 16 + fq * 4;
      #pragma unroll
      for (int r = 0; r < 4; ++r)
        C[(gm + r) * (size_t)N + gn] = acc[m][n][r] + bv;  // C row = m, col = n (m89-verified)
    }
  }
}

// ---------------- one BiLSTM layer: 64 blocks = (dir, batch) chains ----------------
// gates_in [4096][3200] f32 (bias already added), Whh f16 [2][1600][400],
// h_out f16 [4096][800] (dir d -> cols d*400..)
__global__ __launch_bounds__(1024) void lstm_layer_k(
    const float* __restrict__ gates_in,
    const f16* __restrict__ Whh,
    f16* __restrict__ h_out)
{
  const int blk = blockIdx.x;            // d*32 + b
  const int d = blk >> 5, b = blk & 31;
  const int tid = threadIdx.x;
  __shared__ __align__(16) f16 h_lds[HH];
  __shared__ float c_lds[HH];
  __shared__ float g_lds[1600];
  for (int i = tid; i < HH; i += 1024) { h_lds[i] = (f16)0.f; c_lds[i] = 0.f; }
  __syncthreads();
  const f16* W1 = Whh + (size_t)d * 1600 * HH + (size_t)tid * HH;  // row tid
  const f16* W2 = W1 + (size_t)1024 * HH;                          // row 1024+tid
  const bool two = tid < 576;  // wave-uniform (576 = 9*64)
  for (int s = 0; s < 128; ++s) {
    const int t = d ? (127 - s) : s;
    const float* grow = gates_in + (size_t)(b * 128 + t) * GN + d * 1600;
    const unsigned* hp = (const unsigned*)h_lds;   // 200 packed f16x2
    float a1 = grow[tid];
    if (two) {
      float a2 = grow[1024 + tid];
      #pragma unroll 10
      for (int kk = 0; kk < 200; kk += 4) {
        const uint4 hv = *(const uint4*)(hp + kk);
        const uint4 w1 = *(const uint4*)(W1 + kk * 2);
        const uint4 w2 = *(const uint4*)(W2 + kk * 2);
        a1 = fdot2u(w1.x, hv.x, a1); a1 = fdot2u(w1.y, hv.y, a1);
        a1 = fdot2u(w1.z, hv.z, a1); a1 = fdot2u(w1.w, hv.w, a1);
        a2 = fdot2u(w2.x, hv.x, a2); a2 = fdot2u(w2.y, hv.y, a2);
        a2 = fdot2u(w2.z, hv.z, a2); a2 = fdot2u(w2.w, hv.w, a2);
      }
      g_lds[tid] = a1; g_lds[1024 + tid] = a2;
    } else {
      #pragma unroll 10
      for (int kk = 0; kk < 200; kk += 4) {
        const uint4 hv = *(const uint4*)(hp + kk);
        const uint4 w1 = *(const uint4*)(W1 + kk * 2);
        a1 = fdot2u(w1.x, hv.x, a1); a1 = fdot2u(w1.y, hv.y, a1);
        a1 = fdot2u(w1.z, hv.z, a1); a1 = fdot2u(w1.w, hv.w, a1);
      }
      g_lds[tid] = a1;
    }
    __syncthreads();
    if (tid < HH) {
      const float gi = sigf(g_lds[tid]);
      const float gf = sigf(g_lds[400 + tid]);
      const float gg = tanhf_(g_lds[800 + tid]);
      const float go = sigf(g_lds[1200 + tid]);
      const float c = gf * c_lds[tid] + gi * gg;
      c_lds[tid] = c;
      const float h = go * tanhf_(c);
      h_lds[tid] = (f16)h;
      h_out[(size_t)(b * 128 + t) * 800 + d * 400 + tid] = (f16)h;
    }
    __syncthreads();
  }
}

// ---------------- tail: s_h[r] = sum tanh(feat[r][0:512])*wo[0:512]; s_m likewise
__global__ __launch_bounds__(256) void tail_k(const float* __restrict__ feat,
                                              const float* __restrict__ wo,
                                              float* __restrict__ s_h,
                                              float* __restrict__ s_m)
{
  const int r = blockIdx.x;          // 4096
  const int tid = threadIdx.x;       // 256; waves 0-1 -> head half, 2-3 -> modif half
  const float* fr = feat + (size_t)r * 1024;
  float sum = 0.f;
  const int n0 = tid * 4;
  #pragma unroll
  for (int j = 0; j < 4; ++j) sum += tanhf_(fr[n0 + j]) * wo[n0 + j];
  #pragma unroll
  for (int off = 32; off > 0; off >>= 1) sum += __shfl_down(sum, off, 64);
  __shared__ float red[4];
  if ((tid & 63) == 0) red[tid >> 6] = sum;
  __syncthreads();
  if (tid == 0)       s_h[r] = red[0] + red[1];
  else if (tid == 64) s_m[r] = red[2] + red[3];
}

__global__ void score_k(const float* __restrict__ s_h, const float* __restrict__ s_m,
                        const float* __restrict__ bo, float* __restrict__ out)
{
  const int bh = blockIdx.x;     // b*T + h, 4096
  const int m = threadIdx.x;     // 128
  out[(size_t)bh * 128 + m] = s_h[bh] + s_m[(bh & ~127) + m] + bo[0];
}

// ---------------- launch ----------------
extern "C" void kernel_launch(void* const* d_in, const int* in_sizes, int n_in,
                              void* d_out, int out_size, void* d_ws, size_t ws_size,
                              hipStream_t stream)
{
  const int*   wt   = (const int*)d_in[0];
  const int*   pt   = (const int*)d_in[2];
  const float* we   = (const float*)d_in[3];
  const float* pe   = (const float*)d_in[4];
  const float* Wih0 = (const float*)d_in[5];
  const float* Whh0 = (const float*)d_in[6];
  const float* b0   = (const float*)d_in[7];
  const float* Wih1 = (const float*)d_in[8];
  const float* Whh1 = (const float*)d_in[9];
  const float* b1   = (const float*)d_in[10];
  const float* Wh   = (const float*)d_in[11];
  const float* bh   = (const float*)d_in[12];
  const float* Wm   = (const float*)d_in[13];
  const float* bm   = (const float*)d_in[14];
  const float* Wo   = (const float*)d_in[15];
  const float* bo   = (const float*)d_in[16];
  float* out = (float*)d_out;

  char* p = (char*)d_ws;
  auto alloc = [&](size_t bytes) { char* q = p; p += (bytes + 255) & ~(size_t)255; return q; };
  f16*   x0    = (f16*)alloc((size_t)4096 * 416 * 2);
  f16*   wih0  = (f16*)alloc((size_t)3200 * 416 * 2);
  f16*   whh0  = (f16*)alloc((size_t)3200 * 400 * 2);
  f16*   wih1  = (f16*)alloc((size_t)3200 * 800 * 2);
  f16*   whh1  = (f16*)alloc((size_t)3200 * 400 * 2);
  f16*   whm   = (f16*)alloc((size_t)1024 * 800 * 2);
  float* bhm   = (float*)alloc(1024 * 4);
  float* sh    = (float*)alloc(4096 * 4);
  float* sm    = (float*)alloc(4096 * 4);
  f16*   h1    = (f16*)alloc((size_t)4096 * 800 * 2);
  f16*   h2    = (f16*)alloc((size_t)4096 * 800 * 2);
  float* gates = (float*)alloc((size_t)4096 * 3200 * 4);
  float* feat  = (float*)gates;   // alias: gates are dead once layer-1 recurrence ran

  // weight prep (all independent)
  embed_k<<<4096, 128, 0, stream>>>(wt, pt, we, pe, x0);
  convpad_k<<<1024, 256, 0, stream>>>(Wih0, wih0, 3200, 400, 416);
  convpad_k<<<1024, 256, 0, stream>>>(Whh0, whh0, 3200, 400, 400);
  convpad_k<<<1024, 256, 0, stream>>>(Wih1, wih1, 3200, 800, 800);
  convpad_k<<<1024, 256, 0, stream>>>(Whh1, whh1, 3200, 400, 400);
  convpad_k<<<1024, 256, 0, stream>>>(Wh, whm, 512, 800, 800);
  convpad_k<<<1024, 256, 0, stream>>>(Wm, whm + (size_t)512 * 800, 512, 800, 800);
  biascat_k<<<1, 1024, 0, stream>>>(bh, bm, bhm);

  // layer 0
  gemm_f16_nt<<<dim3(25, 32), 256, 0, stream>>>(x0, wih0, b0, gates, 4096, 3200, 416);
  lstm_layer_k<<<64, 1024, 0, stream>>>(gates, whh0, h1);
  // layer 1
  gemm_f16_nt<<<dim3(25, 32), 256, 0, stream>>>(h1, wih1, b1, gates, 4096, 3200, 800);
  lstm_layer_k<<<64, 1024, 0, stream>>>(gates, whh1, h2);
  // head/modif features + scorer
  gemm_f16_nt<<<dim3(8, 32), 256, 0, stream>>>(h2, whm, bhm, feat, 4096, 1024, 800);
  tail_k<<<4096, 256, 0, stream>>>(feat, Wo, sh, sm);
  score_k<<<4096, 128, 0, stream>>>(sh, sm, bo, out);
}

// Round 2
// 1777.984 us; speedup vs baseline: 2.9208x; 2.9208x over previous
//
#include <hip/hip_runtime.h>

#define DEV __device__ __forceinline__

typedef _Float16 f16;
typedef _Float16 f16x8 __attribute__((ext_vector_type(8)));
typedef float f32x4 __attribute__((ext_vector_type(4)));

static constexpr int K0P = 416;   // layer0 input dim 400 padded to 13*32
static constexpr int NB  = 16;    // blocks per direction in recurrence
static constexpr int WKP = 424;   // padded K for W/h LDS rows (53*16B: odd segs -> no bank conflicts)
static constexpr int NRW = 128;   // padded gate rows per block (100 real)
static constexpr int SMEM_LSTM = NRW*WKP*2 + 32*WKP*2 + NRW*33*4 + 800*4; // 155,776 B

// ---------------- math helpers ----------------
DEV float sigf(float x) { return 1.f / (1.f + __expf(-x)); }
DEV float tanhf_(float x) {
  x = fminf(10.f, fmaxf(-10.f, x));
  float e = __expf(2.f * x);
  return (e - 1.f) / (e + 1.f);
}

// ---------------- embedding gather -> x0 f16 [4096][416] ----------------
__global__ void embed_k(const int* __restrict__ wt, const int* __restrict__ pt,
                        const float* __restrict__ we, const float* __restrict__ pe,
                        f16* __restrict__ x0)
{
  const int r = blockIdx.x;       // b*T+t
  const int tid = threadIdx.x;    // 128
  const int w = wt[r], p = pt[r];
  const float* wrow = we + (size_t)w * 300;
  const float* prow = pe + (size_t)p * 100;
  f16* xr = x0 + (size_t)r * K0P;
  for (int k = tid; k < K0P; k += 128) {
    float v = (k < 300) ? wrow[k] : (k < 400 ? prow[k - 300] : 0.f);
    xr[k] = (f16)v;
  }
}

// ---------------- f32 -> f16 with optional K padding ----------------
__global__ void convpad_k(const float* __restrict__ src, f16* __restrict__ dst,
                          int rows, int K, int KP)
{
  const size_t total = (size_t)rows * KP;
  for (size_t i = (size_t)blockIdx.x * blockDim.x + threadIdx.x; i < total;
       i += (size_t)gridDim.x * blockDim.x) {
    int r = (int)(i / KP), k = (int)(i % KP);
    dst[i] = (f16)(k < K ? src[(size_t)r * K + k] : 0.f);
  }
}

// Whh f32 [2][1600][400] -> reordered f16 [2][NB][NRW][WKP]
// block-row r = g*28 + uu (uu<25), unit u = blk*25+uu, src row = g*400+u
__global__ void whh_reorder_k(const float* __restrict__ src, f16* __restrict__ dst)
{
  const int total = 2 * NB * NRW * WKP;
  for (int i = blockIdx.x * blockDim.x + threadIdx.x; i < total;
       i += gridDim.x * blockDim.x) {
    int k = i % WKP, r = (i / WKP) % NRW, blk = (i / (WKP * NRW)) % NB,
        d = i / (WKP * NRW * NB);
    int g = r / 28, uu = r % 28;
    float v = 0.f;
    if (r < 112 && uu < 25 && k < 400)
      v = src[((size_t)d * 1600 + g * 400 + blk * 25 + uu) * 400 + k];
    dst[i] = (f16)v;
  }
}

__global__ void biascat_k(const float* __restrict__ bh, const float* __restrict__ bm,
                          float* __restrict__ bhm)
{
  int i = threadIdx.x;  // 1024
  bhm[i] = i < 512 ? bh[i] : bm[i - 512];
}

__global__ void zero_k(int* __restrict__ p, int n)
{
  int i = blockIdx.x * blockDim.x + threadIdx.x;
  if (i < n) p[i] = 0;
}

// ---------------- GEMM: C[M][N] = A[M][KP] * B[N][KP]^T + bias[n], f16 in, f32 out
__global__ __launch_bounds__(256) void gemm_f16_nt(
    const f16* __restrict__ A, const f16* __restrict__ Bw,
    const float* __restrict__ bias, float* __restrict__ C,
    int M, int N, int KP)
{
  __shared__ __align__(16) f16 As[128][40];
  __shared__ __align__(16) f16 Bs[128][40];
  const int tid = threadIdx.x;
  const int bn = blockIdx.x, bm = blockIdx.y;
  const int lane = tid & 63, wid = tid >> 6;
  const int wr = wid >> 1, wc = wid & 1;
  const int srow = tid >> 1, shalf = tid & 1;
  const f16* Ap = A + (size_t)(bm * 128 + srow) * KP + shalf * 16;
  const f16* Bp = Bw + (size_t)(bn * 128 + srow) * KP + shalf * 16;
  const int fr = lane & 15, fq = lane >> 4;
  f32x4 acc[4][4] = {};
  for (int kt = 0; kt < KP; kt += 32) {
    __syncthreads();
    *(uint4*)&As[srow][shalf * 16]     = *(const uint4*)(Ap + kt);
    *(uint4*)&As[srow][shalf * 16 + 8] = *(const uint4*)(Ap + kt + 8);
    *(uint4*)&Bs[srow][shalf * 16]     = *(const uint4*)(Bp + kt);
    *(uint4*)&Bs[srow][shalf * 16 + 8] = *(const uint4*)(Bp + kt + 8);
    __syncthreads();
    f16x8 af[4], bf[4];
    #pragma unroll
    for (int m = 0; m < 4; ++m) af[m] = *(const f16x8*)&As[wr * 64 + m * 16 + fr][fq * 8];
    #pragma unroll
    for (int n = 0; n < 4; ++n) bf[n] = *(const f16x8*)&Bs[wc * 64 + n * 16 + fr][fq * 8];
    #pragma unroll
    for (int m = 0; m < 4; ++m)
      #pragma unroll
      for (int n = 0; n < 4; ++n)
        acc[m][n] = __builtin_amdgcn_mfma_f32_16x16x32_f16(af[m], bf[n], acc[m][n], 0, 0, 0);
  }
  #pragma unroll
  for (int n = 0; n < 4; ++n) {
    const int gn = bn * 128 + wc * 64 + n * 16 + fr;
    const float bv = bias ? bias[gn] : 0.f;
    #pragma unroll
    for (int m = 0; m < 4; ++m) {
      const size_t gm = (size_t)bm * 128 + wr * 64 + m * 16 + fq * 4;
      #pragma unroll
      for (int r = 0; r < 4; ++r)
        C[(gm + r) * (size_t)N + gn] = acc[m][n][r] + bv;
    }
  }
}

// ---------------- recurrence: 32 blocks = 2 dirs x 16 unit-slices ----------------
// gates [4096][3200] f32 (x@Wih^T + b, original col order d*1600 + g*400 + u)
// whh_r [2][NB][NRW][WKP] f16 (gate-reordered, padded)
// h_out [4096][800] f16 ; h_glob [2][128][32][400] f16 exchange ; cnt [2][128]
__global__ __launch_bounds__(256) void lstm_mfma_k(
    const float* __restrict__ gates,
    const f16* __restrict__ whh_r,
    f16* __restrict__ h_out,
    f16* __restrict__ h_glob,
    int* __restrict__ cnt)
{
  extern __shared__ char smem[];
  f16*   W_lds = (f16*)smem;                               // [NRW][WKP]
  f16*   h_lds = (f16*)(smem + NRW * WKP * 2);             // [32][WKP]
  float* g_lds = (float*)(smem + NRW * WKP * 2 + 32 * WKP * 2); // [NRW][33]
  float* c_lds = g_lds + NRW * 33;                         // [800]

  const int d = blockIdx.x >> 4, blk = blockIdx.x & 15;
  const int tid = threadIdx.x;
  const int lane = tid & 63, w = tid >> 6;
  const int fr = lane & 15, fq = lane >> 4;
  const int mf0 = w, mf1 = w + 4;
  int* mycnt = cnt + d * 128;

  // W slice -> LDS once (108,544 B = 6784 uint4)
  {
    const uint4* src = (const uint4*)(whh_r + ((size_t)d * NB + blk) * NRW * WKP);
    uint4* dst = (uint4*)W_lds;
    for (int i = tid; i < NRW * WKP / 8; i += 256) dst[i] = src[i];
  }
  {
    uint4 z = {0, 0, 0, 0};
    uint4* dst = (uint4*)h_lds;
    for (int i = tid; i < 32 * WKP / 8; i += 256) dst[i] = z;
    for (int i = tid; i < 800; i += 256) c_lds[i] = 0.f;
  }
  __syncthreads();

  for (int s = 0; s < 128; ++s) {
    const int t = d ? (127 - s) : s;
    if (s > 0) {
      if (tid == 0) {
        while (__hip_atomic_load(&mycnt[s - 1], __ATOMIC_ACQUIRE,
                                 __HIP_MEMORY_SCOPE_AGENT) < NB)
          __builtin_amdgcn_s_sleep(1);
      }
      __syncthreads();
      // stage h_{s-1}: [32][400] -> h_lds[32][WKP] (pads stay 0)
      const uint4* src = (const uint4*)(h_glob + ((size_t)d * 128 + (s - 1)) * 32 * 400);
      for (int i = tid; i < 1600; i += 256) {
        int b = i / 50, seg = i % 50;
        *(uint4*)&h_lds[b * WKP + seg * 8] = src[i];
      }
      __syncthreads();
    }
    // prefetch this step's gate inputs (independent of h) to hide L2/HBM latency
    float gpre[4][4];
    #pragma unroll
    for (int ii = 0; ii < 4; ++ii) {
      int idx = tid + ii * 256;
      if (idx < 800) {
        int b = idx / 25, uu = idx % 25;
        const float* gp = gates + (size_t)(b * 128 + t) * 3200 + d * 1600 + blk * 25 + uu;
        gpre[ii][0] = gp[0];   gpre[ii][1] = gp[400];
        gpre[ii][2] = gp[800]; gpre[ii][3] = gp[1200];
      }
    }
    // g[NRW][32] = W_lds @ h_lds^T
    f32x4 acc[2][2] = {};
    for (int kk = 0; kk < 13; ++kk) {
      const int k0 = kk * 32 + fq * 8;
      f16x8 a0 = *(const f16x8*)&W_lds[(mf0 * 16 + fr) * WKP + k0];
      f16x8 a1 = *(const f16x8*)&W_lds[(mf1 * 16 + fr) * WKP + k0];
      f16x8 b0 = *(const f16x8*)&h_lds[fr * WKP + k0];
      f16x8 b1 = *(const f16x8*)&h_lds[(16 + fr) * WKP + k0];
      acc[0][0] = __builtin_amdgcn_mfma_f32_16x16x32_f16(a0, b0, acc[0][0], 0, 0, 0);
      acc[0][1] = __builtin_amdgcn_mfma_f32_16x16x32_f16(a0, b1, acc[0][1], 0, 0, 0);
      acc[1][0] = __builtin_amdgcn_mfma_f32_16x16x32_f16(a1, b0, acc[1][0], 0, 0, 0);
      acc[1][1] = __builtin_amdgcn_mfma_f32_16x16x32_f16(a1, b1, acc[1][1], 0, 0, 0);
    }
    #pragma unroll
    for (int m = 0; m < 2; ++m) {
      const int row = (m ? mf1 : mf0) * 16 + fq * 4;
      #pragma unroll
      for (int n = 0; n < 2; ++n)
        #pragma unroll
        for (int r = 0; r < 4; ++r)
          g_lds[(row + r) * 33 + n * 16 + fr] = acc[m][n][r];
    }
    __syncthreads();
    // activations for 25 units x 32 batches
    #pragma unroll
    for (int ii = 0; ii < 4; ++ii) {
      int idx = tid + ii * 256;
      if (idx < 800) {
        int b = idx / 25, uu = idx % 25;
        float vi = g_lds[(uu)      * 33 + b] + gpre[ii][0];
        float vf = g_lds[(28 + uu) * 33 + b] + gpre[ii][1];
        float vg = g_lds[(56 + uu) * 33 + b] + gpre[ii][2];
        float vo = g_lds[(84 + uu) * 33 + b] + gpre[ii][3];
        float c = sigf(vf) * c_lds[idx] + sigf(vi) * tanhf_(vg);
        c_lds[idx] = c;
        f16 hf = (f16)(sigf(vo) * tanhf_(c));
        h_glob[((size_t)d * 128 + s) * 32 * 400 + b * 400 + blk * 25 + uu] = hf;
        h_out[(size_t)(b * 128 + t) * 800 + d * 400 + blk * 25 + uu] = hf;
      }
    }
    // publish: drain stores (barrier implies vmcnt(0)), then one agent fence + signal
    __syncthreads();
    if (tid == 0) {
      __threadfence();
      __hip_atomic_fetch_add(&mycnt[s], 1, __ATOMIC_RELEASE, __HIP_MEMORY_SCOPE_AGENT);
    }
  }
}

// ---------------- tail: s_h/s_m = tanh(feat) @ Wo halves ----------------
__global__ __launch_bounds__(256) void tail_k(const float* __restrict__ feat,
                                              const float* __restrict__ wo,
                                              float* __restrict__ s_h,
                                              float* __restrict__ s_m)
{
  const int r = blockIdx.x;
  const int tid = threadIdx.x;
  const float* fr = feat + (size_t)r * 1024;
  float sum = 0.f;
  const int n0 = tid * 4;
  #pragma unroll
  for (int j = 0; j < 4; ++j) sum += tanhf_(fr[n0 + j]) * wo[n0 + j];
  #pragma unroll
  for (int off = 32; off > 0; off >>= 1) sum += __shfl_down(sum, off, 64);
  __shared__ float red[4];
  if ((tid & 63) == 0) red[tid >> 6] = sum;
  __syncthreads();
  if (tid == 0)       s_h[r] = red[0] + red[1];
  else if (tid == 64) s_m[r] = red[2] + red[3];
}

__global__ void score_k(const float* __restrict__ s_h, const float* __restrict__ s_m,
                        const float* __restrict__ bo, float* __restrict__ out)
{
  const int bh = blockIdx.x;
  const int m = threadIdx.x;
  out[(size_t)bh * 128 + m] = s_h[bh] + s_m[(bh & ~127) + m] + bo[0];
}

// ---------------- launch ----------------
extern "C" void kernel_launch(void* const* d_in, const int* in_sizes, int n_in,
                              void* d_out, int out_size, void* d_ws, size_t ws_size,
                              hipStream_t stream)
{
  const int*   wt   = (const int*)d_in[0];
  const int*   pt   = (const int*)d_in[2];
  const float* we   = (const float*)d_in[3];
  const float* pe   = (const float*)d_in[4];
  const float* Wih0 = (const float*)d_in[5];
  const float* Whh0 = (const float*)d_in[6];
  const float* b0   = (const float*)d_in[7];
  const float* Wih1 = (const float*)d_in[8];
  const float* Whh1 = (const float*)d_in[9];
  const float* b1   = (const float*)d_in[10];
  const float* Wh   = (const float*)d_in[11];
  const float* bh   = (const float*)d_in[12];
  const float* Wm   = (const float*)d_in[13];
  const float* bm   = (const float*)d_in[14];
  const float* Wo   = (const float*)d_in[15];
  const float* bo   = (const float*)d_in[16];
  float* out = (float*)d_out;

  char* p = (char*)d_ws;
  auto alloc = [&](size_t bytes) { char* q = p; p += (bytes + 255) & ~(size_t)255; return q; };
  f16*   x0    = (f16*)alloc((size_t)4096 * K0P * 2);
  f16*   wih0  = (f16*)alloc((size_t)3200 * K0P * 2);
  f16*   wih1  = (f16*)alloc((size_t)3200 * 800 * 2);
  f16*   whh0r = (f16*)alloc((size_t)2 * NB * NRW * WKP * 2);
  f16*   whh1r = (f16*)alloc((size_t)2 * NB * NRW * WKP * 2);
  f16*   whm   = (f16*)alloc((size_t)1024 * 800 * 2);
  float* bhm   = (float*)alloc(1024 * 4);
  float* sh    = (float*)alloc(4096 * 4);
  float* sm    = (float*)alloc(4096 * 4);
  f16*   h1    = (f16*)alloc((size_t)4096 * 800 * 2);
  f16*   h2    = (f16*)alloc((size_t)4096 * 800 * 2);
  f16*   hgl   = (f16*)alloc((size_t)2 * 128 * 32 * 400 * 2);
  int*   cnt   = (int*)alloc(512 * 4);
  float* gates = (float*)alloc((size_t)4096 * 3200 * 4);
  float* feat  = (float*)gates;  // gates dead before feature GEMM

  static bool attr_set = false;
  if (!attr_set) {
    hipFuncSetAttribute((const void*)lstm_mfma_k,
                        hipFuncAttributeMaxDynamicSharedMemorySize, SMEM_LSTM);
    attr_set = true;
  }

  zero_k<<<2, 256, 0, stream>>>(cnt, 512);
  embed_k<<<4096, 128, 0, stream>>>(wt, pt, we, pe, x0);
  convpad_k<<<1024, 256, 0, stream>>>(Wih0, wih0, 3200, 400, K0P);
  convpad_k<<<1024, 256, 0, stream>>>(Wih1, wih1, 3200, 800, 800);
  convpad_k<<<1024, 256, 0, stream>>>(Wh, whm, 512, 800, 800);
  convpad_k<<<1024, 256, 0, stream>>>(Wm, whm + (size_t)512 * 800, 512, 800, 800);
  whh_reorder_k<<<1024, 256, 0, stream>>>(Whh0, whh0r);
  whh_reorder_k<<<1024, 256, 0, stream>>>(Whh1, whh1r);
  biascat_k<<<1, 1024, 0, stream>>>(bh, bm, bhm);

  // layer 0
  gemm_f16_nt<<<dim3(25, 32), 256, 0, stream>>>(x0, wih0, b0, gates, 4096, 3200, K0P);
  lstm_mfma_k<<<32, 256, SMEM_LSTM, stream>>>(gates, whh0r, h1, hgl, cnt);
  // layer 1
  gemm_f16_nt<<<dim3(25, 32), 256, 0, stream>>>(h1, wih1, b1, gates, 4096, 3200, 800);
  lstm_mfma_k<<<32, 256, SMEM_LSTM, stream>>>(gates, whh1r, h2, hgl, cnt + 256);
  // features + scorer
  gemm_f16_nt<<<dim3(8, 32), 256, 0, stream>>>(h2, whm, bhm, feat, 4096, 1024, 800);
  tail_k<<<4096, 256, 0, stream>>>(feat, Wo, sh, sm);
  score_k<<<4096, 128, 0, stream>>>(sh, sm, bo, out);
}